// Round 2
// baseline (5772.032 us; speedup 1.0000x reference)
//
#include <hip/hip_runtime.h>
#include <hip/hip_bf16.h>
#include <cstdint>

#define CB 16
#define CK 64
#define CW 2048
#define CL 2112
#define CD 512
#define CDH 256
#define CDFF 2048
#define CNL 4
#define CROWS (CB*CL)
#define GB 4                 // batches per attention group
#define RCH (CROWS/4)        // FFN row chunk (8448 = 66*128)

typedef __attribute__((ext_vector_type(8))) short bf16x8;
typedef __attribute__((ext_vector_type(4))) float f32x4;

__device__ __forceinline__ float bf2f(unsigned short u) {
    union { unsigned int i; float f; } x; x.i = ((unsigned int)u) << 16; return x.f;
}

__device__ __forceinline__ void load_lds16(const void* g, void* l) {
    __builtin_amdgcn_global_load_lds(
        (const __attribute__((address_space(1))) void*)g,
        (__attribute__((address_space(3))) void*)l, 16, 0, 0);
}

// ---------------- GEMM: C[MxN] = A[MxK] @ Bt[NxK]^T, bf16 in, fp32 acc ----------------
// epi 0: C bf16 = acc
// epi 1: C bf16 = relu(acc + bias[col])
// epi 2: C bf16 = acc * scale
// epi 3: C fp32 += acc + bias[col]   (in-place residual)
#define BM 128
#define BN 128
#define BKG 64

__global__ __launch_bounds__(256) void gemm_bt(
    const short* __restrict__ A, const short* __restrict__ Bt, void* __restrict__ C,
    const float* __restrict__ bias, int M, int N, int Kd,
    int lda, int ldb, int ldc, long sA, long sB, long sC, float scale, int epi)
{
    __shared__ short lA[BM * BKG];
    __shared__ short lB[BN * BKG];
    const int tid = threadIdx.x;
    const int wave = tid >> 6, lane = tid & 63;
    const int wy = wave >> 1, wx = wave & 1;
    const int lr = lane & 15, quad = lane >> 4;
    const int m0 = blockIdx.y * BM, n0 = blockIdx.x * BN;
    const int z = blockIdx.z;
    const short* Ab = A + (size_t)z * sA;
    const short* Bb = Bt + (size_t)z * sB;

    f32x4 acc[4][4];
#pragma unroll
    for (int i = 0; i < 4; i++)
#pragma unroll
        for (int j = 0; j < 4; j++) acc[i][j] = (f32x4){0.f, 0.f, 0.f, 0.f};

    const int sRow = lane >> 3;        // 0..7
    const int sCol = (lane & 7) * 8;   // 0..56 (shorts)

    for (int k0 = 0; k0 < Kd; k0 += BKG) {
        __syncthreads();
#pragma unroll
        for (int n = 0; n < 4; ++n) {
            const int c = wave * 4 + n;
            int ar = m0 + c * 8 + sRow; if (ar > M - 1) ar = M - 1;
            load_lds16(Ab + (size_t)ar * lda + k0 + sCol, lA + c * 512);
            int br = n0 + c * 8 + sRow; if (br > N - 1) br = N - 1;
            load_lds16(Bb + (size_t)br * ldb + k0 + sCol, lB + c * 512);
        }
        __syncthreads();
#pragma unroll
        for (int kk = 0; kk < BKG; kk += 32) {
            bf16x8 av[4], bv[4];
#pragma unroll
            for (int i = 0; i < 4; i++)
                av[i] = *(const bf16x8*)&lA[(wy * 64 + i * 16 + lr) * BKG + kk + quad * 8];
#pragma unroll
            for (int j = 0; j < 4; j++)
                bv[j] = *(const bf16x8*)&lB[(wx * 64 + j * 16 + lr) * BKG + kk + quad * 8];
#pragma unroll
            for (int i = 0; i < 4; i++)
#pragma unroll
                for (int j = 0; j < 4; j++)
                    acc[i][j] = __builtin_amdgcn_mfma_f32_16x16x32_bf16(av[i], bv[j], acc[i][j], 0, 0, 0);
        }
    }

    const int colBase = n0 + wx * 64 + lr;
    if (epi == 3) {
        float* Cp = (float*)C + (size_t)z * sC;
#pragma unroll
        for (int i = 0; i < 4; i++) {
            const int row0 = m0 + wy * 64 + i * 16 + quad * 4;
#pragma unroll
            for (int j = 0; j < 4; j++) {
                const int col = colBase + j * 16;
                const float bv_ = bias ? bias[col] : 0.f;
#pragma unroll
                for (int r = 0; r < 4; r++) {
                    const int row = row0 + r;
                    if (row < M) Cp[(size_t)row * ldc + col] += acc[i][j][r] + bv_;
                }
            }
        }
    } else {
        __hip_bfloat16* Cp = (__hip_bfloat16*)C + (size_t)z * sC;
#pragma unroll
        for (int i = 0; i < 4; i++) {
            const int row0 = m0 + wy * 64 + i * 16 + quad * 4;
#pragma unroll
            for (int j = 0; j < 4; j++) {
                const int col = colBase + j * 16;
                const float bv_ = (epi == 1) ? bias[col] : 0.f;
#pragma unroll
                for (int r = 0; r < 4; r++) {
                    const int row = row0 + r;
                    if (row < M) {
                        float v = acc[i][j][r];
                        if (epi == 1) { v += bv_; v = v > 0.f ? v : 0.f; }
                        else if (epi == 2) v *= scale;
                        Cp[(size_t)row * ldc + col] = __float2bfloat16(v);
                    }
                }
            }
        }
    }
}

// ---------------- embedding ----------------
__global__ void embed_kernel(const int* __restrict__ cache, const int* __restrict__ seq,
                             const float* __restrict__ item, const float* __restrict__ cpos,
                             const float* __restrict__ spos, const float* __restrict__ seg,
                             float* __restrict__ h)
{
    const int row = blockIdx.x;
    const int b = row / CL, t = row - b * CL;
    const int d = threadIdx.x * 4;
    int id; const float* pos; const float* sg;
    if (t < CK) { id = cache[b * CK + t]; pos = cpos + (size_t)t * CD; sg = seg; }
    else { const int tt = t - CK; id = seq[b * CW + tt]; pos = spos + (size_t)tt * CD; sg = seg + CD; }
    const float4 ev = *(const float4*)(item + (size_t)id * CD + d);
    const float4 pv = *(const float4*)(pos + d);
    const float4 sv = *(const float4*)(sg + d);
    float4 r; r.x = ev.x + pv.x + sv.x; r.y = ev.y + pv.y + sv.y;
    r.z = ev.z + pv.z + sv.z; r.w = ev.w + pv.w + sv.w;
    *(float4*)(h + (size_t)row * CD + d) = r;
}

// ---------------- layernorm -> bf16 ----------------
__global__ __launch_bounds__(256) void ln_kernel(const float* __restrict__ h, const float* __restrict__ g,
                                                 const float* __restrict__ bb, __hip_bfloat16* __restrict__ out)
{
    const int row = blockIdx.x;
    const float* x = h + (size_t)row * CD;
    const int tid = threadIdx.x, wv = tid >> 6, lane = tid & 63;
    const float2 v = *(const float2*)(x + tid * 2);
    float s = v.x + v.y, s2 = v.x * v.x + v.y * v.y;
    __shared__ float red[8];
#pragma unroll
    for (int off = 32; off; off >>= 1) { s += __shfl_down(s, off); s2 += __shfl_down(s2, off); }
    if (lane == 0) { red[wv] = s; red[4 + wv] = s2; }
    __syncthreads();
    s = red[0] + red[1] + red[2] + red[3];
    s2 = red[4] + red[5] + red[6] + red[7];
    const float mu = s * (1.f / CD);
    const float var = s2 * (1.f / CD) - mu * mu;
    const float rs = rsqrtf(var + 1e-5f);
    const float2 gg = *(const float2*)(g + tid * 2);
    const float2 bv = *(const float2*)(bb + tid * 2);
    out[(size_t)row * CD + tid * 2 + 0] = __float2bfloat16((v.x - mu) * rs * gg.x + bv.x);
    out[(size_t)row * CD + tid * 2 + 1] = __float2bfloat16((v.y - mu) * rs * gg.y + bv.y);
}

// ---------------- masked softmax over W, in place (bf16) ----------------
__global__ __launch_bounds__(256) void softmax_kernel(__hip_bfloat16* __restrict__ sc)
{
    const int row = blockIdx.x;
    const int t = row % CL;
    const int limit = (t < CK) ? CW : (t - (CK - 1));
    __hip_bfloat16* pr = sc + (size_t)row * CW;
    const int tid = threadIdx.x, wv = tid >> 6, lane = tid & 63;
    float v[8];
    float mx = -1e30f;
#pragma unroll
    for (int k = 0; k < 8; k++) {
        const int j = k * 256 + tid;
        const float x = (j < limit) ? __bfloat162float(pr[j]) : -1e30f;
        v[k] = x; mx = fmaxf(mx, x);
    }
    __shared__ float red[8];
#pragma unroll
    for (int off = 32; off; off >>= 1) mx = fmaxf(mx, __shfl_down(mx, off));
    if (lane == 0) red[wv] = mx;
    __syncthreads();
    mx = fmaxf(fmaxf(red[0], red[1]), fmaxf(red[2], red[3]));
    float s = 0.f;
#pragma unroll
    for (int k = 0; k < 8; k++) {
        const int j = k * 256 + tid;
        const float e = (j < limit) ? __expf(v[k] - mx) : 0.f;
        v[k] = e; s += e;
    }
#pragma unroll
    for (int off = 32; off; off >>= 1) s += __shfl_down(s, off);
    if (lane == 0) red[4 + wv] = s;
    __syncthreads();
    s = red[4] + red[5] + red[6] + red[7];
    const float rinv = 1.f / s;
#pragma unroll
    for (int k = 0; k < 8; k++) {
        const int j = k * 256 + tid;
        pr[j] = __float2bfloat16(v[k] * rinv);
    }
}

// ---------------- attention over 64 cache keys (branch B), wave per row ----------------
__global__ __launch_bounds__(256) void attnb_kernel(const short* __restrict__ qb, const short* __restrict__ kb,
                                                    const short* __restrict__ vb, __hip_bfloat16* __restrict__ attn)
{
    __shared__ float ps[4][64];
    const int wave = threadIdx.x >> 6, lane = threadIdx.x & 63;
    const int b = blockIdx.y;
    const int t = blockIdx.x * 4 + wave;
    const size_t row = (size_t)b * CL + t;
    const short* q = qb + row * CDH;
    const short* k = kb + ((size_t)b * 64 + lane) * CDH;
    float s = 0.f;
#pragma unroll 8
    for (int d = 0; d < CDH; d += 4) {
        const ushort4 qv = *(const ushort4*)(const void*)(q + d);
        const ushort4 kv = *(const ushort4*)(const void*)(k + d);
        s += bf2f(qv.x) * bf2f(kv.x) + bf2f(qv.y) * bf2f(kv.y)
           + bf2f(qv.z) * bf2f(kv.z) + bf2f(qv.w) * bf2f(kv.w);
    }
    s *= 0.0625f;
    float m = s;
#pragma unroll
    for (int off = 32; off; off >>= 1) m = fmaxf(m, __shfl_xor(m, off));
    const float e = __expf(s - m);
    float sum = e;
#pragma unroll
    for (int off = 32; off; off >>= 1) sum += __shfl_xor(sum, off);
    ps[wave][lane] = e / sum;
    __syncthreads();
    float a0 = 0, a1 = 0, a2 = 0, a3 = 0;
    const short* vbase = vb + (size_t)b * 64 * CDH + lane * 4;
#pragma unroll 8
    for (int j = 0; j < 64; j++) {
        const float pj = ps[wave][j];
        const ushort4 vv = *(const ushort4*)(const void*)(vbase + (size_t)j * CDH);
        a0 += pj * bf2f(vv.x); a1 += pj * bf2f(vv.y); a2 += pj * bf2f(vv.z); a3 += pj * bf2f(vv.w);
    }
    __hip_bfloat16* o = attn + row * CD + CDH + lane * 4;
    o[0] = __float2bfloat16(a0); o[1] = __float2bfloat16(a1);
    o[2] = __float2bfloat16(a2); o[3] = __float2bfloat16(a3);
}

// ---------------- final LN + logits ----------------
__global__ __launch_bounds__(256) void final_kernel(const float* __restrict__ h, const float* __restrict__ g,
                                                    const float* __restrict__ bb, const float* __restrict__ wev,
                                                    const float* __restrict__ bev, float* __restrict__ out)
{
    const int idx = blockIdx.x;
    const int b = idx >> 6, t = idx & 63;
    const float* x = h + ((size_t)b * CL + t) * CD;
    const int tid = threadIdx.x, wv = tid >> 6, lane = tid & 63;
    const float2 v = *(const float2*)(x + tid * 2);
    float s = v.x + v.y, s2 = v.x * v.x + v.y * v.y;
    __shared__ float red[8];
#pragma unroll
    for (int off = 32; off; off >>= 1) { s += __shfl_down(s, off); s2 += __shfl_down(s2, off); }
    if (lane == 0) { red[wv] = s; red[4 + wv] = s2; }
    __syncthreads();
    s = red[0] + red[1] + red[2] + red[3];
    s2 = red[4] + red[5] + red[6] + red[7];
    const float mu = s * (1.f / CD);
    const float var = s2 * (1.f / CD) - mu * mu;
    const float rs = rsqrtf(var + 1e-5f);
    const float2 gg = *(const float2*)(g + tid * 2);
    const float2 bv = *(const float2*)(bb + tid * 2);
    const float2 wv2 = *(const float2*)(wev + tid * 2);
    float val = ((v.x - mu) * rs * gg.x + bv.x) * wv2.x + ((v.y - mu) * rs * gg.y + bv.y) * wv2.y;
#pragma unroll
    for (int off = 32; off; off >>= 1) val += __shfl_down(val, off);
    __syncthreads();
    if (lane == 0) red[wv] = val;
    __syncthreads();
    if (tid == 0) out[idx] = red[0] + red[1] + red[2] + red[3] + bev[0];
}

// ---------------- transpose-convert: fp32 [Z][R][C] -> bf16 [Z][C][R] ----------------
__global__ void transpose_f32(const float* __restrict__ in, __hip_bfloat16* __restrict__ out, int R, int Cc)
{
    __shared__ float tile[32][33];
    const size_t zo = (size_t)blockIdx.z * R * Cc;
    const int c0 = blockIdx.x * 32, r0 = blockIdx.y * 32;
    const int tx = threadIdx.x, ty = threadIdx.y;
#pragma unroll
    for (int i = ty; i < 32; i += 8)
        tile[i][tx] = in[zo + (size_t)(r0 + i) * Cc + c0 + tx];
    __syncthreads();
#pragma unroll
    for (int i = ty; i < 32; i += 8)
        out[zo + (size_t)(c0 + i) * R + r0 + tx] = __float2bfloat16(tile[tx][i]);
}

extern "C" void kernel_launch(void* const* d_in, const int* in_sizes, int n_in,
                              void* d_out, int out_size, void* d_ws, size_t ws_size,
                              hipStream_t stream)
{
    const int*   cache = (const int*)d_in[0];
    const int*   seq   = (const int*)d_in[1];
    const float* item  = (const float*)d_in[2];
    const float* cpos  = (const float*)d_in[3];
    const float* spos  = (const float*)d_in[4];
    const float* seg   = (const float*)d_in[5];
    const float* wq_s  = (const float*)d_in[6];
    const float* wk_s  = (const float*)d_in[7];
    const float* wv_s  = (const float*)d_in[8];
    const float* wq_c  = (const float*)d_in[9];
    const float* wk_c  = (const float*)d_in[10];
    const float* wv_c  = (const float*)d_in[11];
    const float* w_out = (const float*)d_in[12];
    const float* b_out = (const float*)d_in[13];
    const float* ln1_g = (const float*)d_in[14];
    const float* ln1_b = (const float*)d_in[15];
    const float* ln2_g = (const float*)d_in[16];
    const float* ln2_b = (const float*)d_in[17];
    const float* w_ff1 = (const float*)d_in[18];
    const float* b_ff1 = (const float*)d_in[19];
    const float* w_ff2 = (const float*)d_in[20];
    const float* b_ff2 = (const float*)d_in[21];
    const float* fin_g = (const float*)d_in[22];
    const float* fin_b = (const float*)d_in[23];
    const float* w_ev  = (const float*)d_in[24];
    const float* b_ev  = (const float*)d_in[25];

    // ---- workspace layout: ~222 MiB total ----
    char* p = (char*)d_ws;
    auto alloc = [&](size_t bytes) { char* r = p; p += (bytes + 255) & ~(size_t)255; return (void*)r; };
    float* h    = (float*)alloc((size_t)CROWS * CD * 4);           // 69.2 MB
    short* hnat = (short*)alloc((size_t)CROWS * CD * 2);           // 34.6 MB  (hn, later attn)
    short* qa   = (short*)alloc((size_t)CROWS * CDH * 2);          // 17.3 MB
    short* qb   = (short*)alloc((size_t)CROWS * CDH * 2);          // 17.3 MB
    short* ka   = (short*)alloc((size_t)CB * CW * CDH * 2);        // 16.8 MB
    short* vt   = (short*)alloc((size_t)CB * CDH * CW * 2);        // 16.8 MB  (V^T per batch)
    short* kb   = (short*)alloc((size_t)CB * 64 * CDH * 2);        // 0.5 MB
    short* vb   = (short*)alloc((size_t)CB * 64 * CDH * 2);        // 0.5 MB
    short* big  = (short*)alloc((size_t)GB * CL * CW * 2);         // 34.6 MB  (scores grp / FF1 chunk)
    short* wqsT = (short*)alloc((size_t)CNL * CDH * CD * 2);
    short* wksT = (short*)alloc((size_t)CNL * CDH * CD * 2);
    short* wvsT = (short*)alloc((size_t)CNL * CDH * CD * 2);
    short* wqcT = (short*)alloc((size_t)CNL * CDH * CD * 2);
    short* wkcT = (short*)alloc((size_t)CNL * CDH * CD * 2);
    short* wvcT = (short*)alloc((size_t)CNL * CDH * CD * 2);
    short* woT  = (short*)alloc((size_t)CNL * CD * CD * 2);
    short* wf1T = (short*)alloc((size_t)CNL * CDFF * CD * 2);
    short* wf2T = (short*)alloc((size_t)CNL * CD * CDFF * 2);

    const dim3 tb(32, 8);
    transpose_f32<<<dim3(CDH / 32, CD / 32, CNL), tb, 0, stream>>>(wq_s, (__hip_bfloat16*)wqsT, CD, CDH);
    transpose_f32<<<dim3(CDH / 32, CD / 32, CNL), tb, 0, stream>>>(wk_s, (__hip_bfloat16*)wksT, CD, CDH);
    transpose_f32<<<dim3(CDH / 32, CD / 32, CNL), tb, 0, stream>>>(wv_s, (__hip_bfloat16*)wvsT, CD, CDH);
    transpose_f32<<<dim3(CDH / 32, CD / 32, CNL), tb, 0, stream>>>(wq_c, (__hip_bfloat16*)wqcT, CD, CDH);
    transpose_f32<<<dim3(CDH / 32, CD / 32, CNL), tb, 0, stream>>>(wk_c, (__hip_bfloat16*)wkcT, CD, CDH);
    transpose_f32<<<dim3(CDH / 32, CD / 32, CNL), tb, 0, stream>>>(wv_c, (__hip_bfloat16*)wvcT, CD, CDH);
    transpose_f32<<<dim3(CD / 32, CD / 32, CNL), tb, 0, stream>>>(w_out, (__hip_bfloat16*)woT, CD, CD);
    transpose_f32<<<dim3(CDFF / 32, CD / 32, CNL), tb, 0, stream>>>(w_ff1, (__hip_bfloat16*)wf1T, CD, CDFF);
    transpose_f32<<<dim3(CD / 32, CDFF / 32, CNL), tb, 0, stream>>>(w_ff2, (__hip_bfloat16*)wf2T, CDFF, CD);

    embed_kernel<<<CROWS, 128, 0, stream>>>(cache, seq, item, cpos, spos, seg, h);

    const int mtilesR = CROWS / 128;          // 264
    const int mtilesL = (CL + 127) / 128;     // 17

    for (int l = 0; l < CNL; ++l) {
        const short* wqsTl = wqsT + (size_t)l * CDH * CD;
        const short* wksTl = wksT + (size_t)l * CDH * CD;
        const short* wvsTl = wvsT + (size_t)l * CDH * CD;
        const short* wqcTl = wqcT + (size_t)l * CDH * CD;
        const short* wkcTl = wkcT + (size_t)l * CDH * CD;
        const short* wvcTl = wvcT + (size_t)l * CDH * CD;
        const short* woTl  = woT  + (size_t)l * CD * CD;
        const short* wf1Tl = wf1T + (size_t)l * CDFF * CD;
        const short* wf2Tl = wf2T + (size_t)l * CD * CDFF;

        ln_kernel<<<CROWS, 256, 0, stream>>>(h, ln1_g + l * CD, ln1_b + l * CD, (__hip_bfloat16*)hnat);

        // q_a / q_b over all rows
        gemm_bt<<<dim3(CDH / 128, mtilesR, 1), 256, 0, stream>>>(hnat, wqsTl, qa, nullptr,
            CROWS, CDH, CD, CD, CD, CDH, 0, 0, 0, 1.f, 0);
        gemm_bt<<<dim3(CDH / 128, mtilesR, 1), 256, 0, stream>>>(hnat, wqcTl, qb, nullptr,
            CROWS, CDH, CD, CD, CD, CDH, 0, 0, 0, 1.f, 0);
        // k_a from hn_seq (batched over 16)
        gemm_bt<<<dim3(CDH / 128, CW / 128, CB), 256, 0, stream>>>(hnat + (size_t)CK * CD, wksTl, ka, nullptr,
            CW, CDH, CD, CD, CD, CDH, (long)CL * CD, 0, (long)CW * CDH, 1.f, 0);
        // k_b, v_b from hn_cache (batched, M=64)
        gemm_bt<<<dim3(CDH / 128, 1, CB), 256, 0, stream>>>(hnat, wkcTl, kb, nullptr,
            64, CDH, CD, CD, CD, CDH, (long)CL * CD, 0, (long)64 * CDH, 1.f, 0);
        gemm_bt<<<dim3(CDH / 128, 1, CB), 256, 0, stream>>>(hnat, wvcTl, vb, nullptr,
            64, CDH, CD, CD, CD, CDH, (long)CL * CD, 0, (long)64 * CDH, 1.f, 0);
        // vt[d][w] = sum_k wv_s[k][d] * hn_seq[w][k]  (V^T directly; A = wv^T, Bt = hn_seq)
        gemm_bt<<<dim3(CW / 128, CDH / 128, CB), 256, 0, stream>>>(wvsTl, hnat + (size_t)CK * CD, vt, nullptr,
            CDH, CW, CD, CD, CD, CW, 0, (long)CL * CD, (long)CDH * CW, 1.f, 0);

        // branch-B attention -> hnat cols [256,512)   (hn fully consumed above)
        attnb_kernel<<<dim3(CL / 4, CB), 256, 0, stream>>>(qb, kb, vb, (__hip_bfloat16*)hnat);

        // branch-A attention in groups of GB batches -> hnat cols [0,256)
        for (int g = 0; g < CB / GB; ++g) {
            const short* qag = qa + (size_t)g * GB * CL * CDH;
            const short* kag = ka + (size_t)g * GB * CW * CDH;
            const short* vtg = vt + (size_t)g * GB * CDH * CW;
            short* attg = hnat + (size_t)g * GB * CL * CD;
            // scores = (q_a @ k_a^T) * scale -> big
            gemm_bt<<<dim3(CW / 128, mtilesL, GB), 256, 0, stream>>>(qag, kag, big, nullptr,
                CL, CW, CDH, CDH, CDH, CW, (long)CL * CDH, (long)CW * CDH, (long)CL * CW, 0.0625f, 2);
            softmax_kernel<<<GB * CL, 256, 0, stream>>>((__hip_bfloat16*)big);
            // out_a = P @ V^T^T -> attn cols 0..255
            gemm_bt<<<dim3(CDH / 128, mtilesL, GB), 256, 0, stream>>>(big, vtg, attg, nullptr,
                CL, CDH, CW, CW, CW, CD, (long)CL * CW, (long)CDH * CW, (long)CL * CD, 1.f, 0);
        }

        // h += attn @ w_out + b_out
        gemm_bt<<<dim3(CD / 128, mtilesR, 1), 256, 0, stream>>>(hnat, woTl, h, b_out + l * CD,
            CROWS, CD, CD, CD, CD, CD, 0, 0, 0, 1.f, 3);

        ln_kernel<<<CROWS, 256, 0, stream>>>(h, ln2_g + l * CD, ln2_b + l * CD, (__hip_bfloat16*)hnat);

        // FFN in 4 row chunks sharing `big`
        for (int c = 0; c < 4; ++c) {
            const size_t r0 = (size_t)c * RCH;
            gemm_bt<<<dim3(CDFF / 128, RCH / 128, 1), 256, 0, stream>>>(hnat + r0 * CD, wf1Tl, big, b_ff1 + l * CDFF,
                RCH, CDFF, CD, CD, CD, CDFF, 0, 0, 0, 1.f, 1);
            gemm_bt<<<dim3(CD / 128, RCH / 128, 1), 256, 0, stream>>>(big, wf2Tl, h + r0 * CD, b_ff2 + l * CD,
                RCH, CD, CDFF, CDFF, CDFF, CD, 0, 0, 0, 1.f, 3);
        }
    }

    final_kernel<<<CB * CK, 256, 0, stream>>>(h, fin_g, fin_b, w_ev, b_ev, (float*)d_out);
}

// Round 3
// 5208.488 us; speedup vs baseline: 1.1082x; 1.1082x over previous
//
#include <hip/hip_runtime.h>
#include <hip/hip_bf16.h>
#include <cstdint>

#define CB 16
#define CK 64
#define CW 2048
#define CL 2112
#define CD 512
#define CDH 256
#define CDFF 2048
#define CNL 4
#define CROWS (CB*CL)
#define GB 4                 // batches per attention group
#define RCH (CROWS/4)        // FFN row chunk (8448 = 66*128)

typedef __attribute__((ext_vector_type(8))) short bf16x8;
typedef __attribute__((ext_vector_type(4))) float f32x4;

__device__ __forceinline__ float bf2f(unsigned short u) {
    union { unsigned int i; float f; } x; x.i = ((unsigned int)u) << 16; return x.f;
}

__device__ __forceinline__ void load_lds16(const void* g, void* l) {
    __builtin_amdgcn_global_load_lds(
        (const __attribute__((address_space(1))) void*)g,
        (__attribute__((address_space(3))) void*)l, 16, 0, 0);
}

// ---------------- GEMM: C[MxN] = A[MxK] @ Bt[NxK]^T, bf16 in, fp32 acc ----------------
// epi 0: C bf16 = acc
// epi 1: C bf16 = relu(acc + bias[col])
// epi 2: C bf16 = acc * scale
// epi 3: C fp32 += acc + bias[col]   (in-place residual)
#define BM 128
#define BN 128
#define BKG 64

__global__ __launch_bounds__(256) void gemm_bt(
    const short* __restrict__ A, const short* __restrict__ Bt, void* __restrict__ C,
    const float* __restrict__ bias, int M, int N, int Kd,
    int lda, int ldb, int ldc, long sA, long sB, long sC, float scale, int epi)
{
    __shared__ short lA[BM * BKG];
    __shared__ short lB[BN * BKG];
    const int tid = threadIdx.x;
    const int wave = tid >> 6, lane = tid & 63;
    const int wy = wave >> 1, wx = wave & 1;
    const int lr = lane & 15, quad = lane >> 4;
    const int m0 = blockIdx.y * BM, n0 = blockIdx.x * BN;
    const int z = blockIdx.z;
    const short* Ab = A + (size_t)z * sA;
    const short* Bb = Bt + (size_t)z * sB;

    f32x4 acc[4][4];
#pragma unroll
    for (int i = 0; i < 4; i++)
#pragma unroll
        for (int j = 0; j < 4; j++) acc[i][j] = (f32x4){0.f, 0.f, 0.f, 0.f};

    const int sRow = lane >> 3;        // 0..7
    const int sCol = (lane & 7) * 8;   // 0..56 (shorts)

    for (int k0 = 0; k0 < Kd; k0 += BKG) {
        __syncthreads();
#pragma unroll
        for (int n = 0; n < 4; ++n) {
            const int c = wave * 4 + n;
            int ar = m0 + c * 8 + sRow; if (ar > M - 1) ar = M - 1;
            load_lds16(Ab + (size_t)ar * lda + k0 + sCol, lA + c * 512);
            int br = n0 + c * 8 + sRow; if (br > N - 1) br = N - 1;
            load_lds16(Bb + (size_t)br * ldb + k0 + sCol, lB + c * 512);
        }
        __syncthreads();
#pragma unroll
        for (int kk = 0; kk < BKG; kk += 32) {
            bf16x8 av[4], bv[4];
#pragma unroll
            for (int i = 0; i < 4; i++)
                av[i] = *(const bf16x8*)&lA[(wy * 64 + i * 16 + lr) * BKG + kk + quad * 8];
#pragma unroll
            for (int j = 0; j < 4; j++)
                bv[j] = *(const bf16x8*)&lB[(wx * 64 + j * 16 + lr) * BKG + kk + quad * 8];
#pragma unroll
            for (int i = 0; i < 4; i++)
#pragma unroll
                for (int j = 0; j < 4; j++)
                    acc[i][j] = __builtin_amdgcn_mfma_f32_16x16x32_bf16(av[i], bv[j], acc[i][j], 0, 0, 0);
        }
    }

    const int colBase = n0 + wx * 64 + lr;
    if (epi == 3) {
        float* Cp = (float*)C + (size_t)z * sC;
#pragma unroll
        for (int i = 0; i < 4; i++) {
            const int row0 = m0 + wy * 64 + i * 16 + quad * 4;
#pragma unroll
            for (int j = 0; j < 4; j++) {
                const int col = colBase + j * 16;
                if (col >= N) continue;
                const float bv_ = bias ? bias[col] : 0.f;
#pragma unroll
                for (int r = 0; r < 4; r++) {
                    const int row = row0 + r;
                    if (row < M) Cp[(size_t)row * ldc + col] += acc[i][j][r] + bv_;
                }
            }
        }
    } else {
        __hip_bfloat16* Cp = (__hip_bfloat16*)C + (size_t)z * sC;
#pragma unroll
        for (int i = 0; i < 4; i++) {
            const int row0 = m0 + wy * 64 + i * 16 + quad * 4;
#pragma unroll
            for (int j = 0; j < 4; j++) {
                const int col = colBase + j * 16;
                if (col >= N) continue;
                const float bv_ = (epi == 1) ? bias[col] : 0.f;
#pragma unroll
                for (int r = 0; r < 4; r++) {
                    const int row = row0 + r;
                    if (row < M) {
                        float v = acc[i][j][r];
                        if (epi == 1) { v += bv_; v = v > 0.f ? v : 0.f; }
                        else if (epi == 2) v *= scale;
                        Cp[(size_t)row * ldc + col] = __float2bfloat16(v);
                    }
                }
            }
        }
    }
}

// ---------------- embedding ----------------
__global__ void embed_kernel(const int* __restrict__ cache, const int* __restrict__ seq,
                             const float* __restrict__ item, const float* __restrict__ cpos,
                             const float* __restrict__ spos, const float* __restrict__ seg,
                             float* __restrict__ h)
{
    const int row = blockIdx.x;
    const int b = row / CL, t = row - b * CL;
    const int d = threadIdx.x * 4;
    int id; const float* pos; const float* sg;
    if (t < CK) { id = cache[b * CK + t]; pos = cpos + (size_t)t * CD; sg = seg; }
    else { const int tt = t - CK; id = seq[b * CW + tt]; pos = spos + (size_t)tt * CD; sg = seg + CD; }
    const float4 ev = *(const float4*)(item + (size_t)id * CD + d);
    const float4 pv = *(const float4*)(pos + d);
    const float4 sv = *(const float4*)(sg + d);
    float4 r; r.x = ev.x + pv.x + sv.x; r.y = ev.y + pv.y + sv.y;
    r.z = ev.z + pv.z + sv.z; r.w = ev.w + pv.w + sv.w;
    *(float4*)(h + (size_t)row * CD + d) = r;
}

// ---------------- layernorm -> bf16 ----------------
__global__ __launch_bounds__(256) void ln_kernel(const float* __restrict__ h, const float* __restrict__ g,
                                                 const float* __restrict__ bb, __hip_bfloat16* __restrict__ out)
{
    const int row = blockIdx.x;
    const float* x = h + (size_t)row * CD;
    const int tid = threadIdx.x, wv = tid >> 6, lane = tid & 63;
    const float2 v = *(const float2*)(x + tid * 2);
    float s = v.x + v.y, s2 = v.x * v.x + v.y * v.y;
    __shared__ float red[8];
#pragma unroll
    for (int off = 32; off; off >>= 1) { s += __shfl_down(s, off); s2 += __shfl_down(s2, off); }
    if (lane == 0) { red[wv] = s; red[4 + wv] = s2; }
    __syncthreads();
    s = red[0] + red[1] + red[2] + red[3];
    s2 = red[4] + red[5] + red[6] + red[7];
    const float mu = s * (1.f / CD);
    const float var = s2 * (1.f / CD) - mu * mu;
    const float rs = rsqrtf(var + 1e-5f);
    const float2 gg = *(const float2*)(g + tid * 2);
    const float2 bv = *(const float2*)(bb + tid * 2);
    out[(size_t)row * CD + tid * 2 + 0] = __float2bfloat16((v.x - mu) * rs * gg.x + bv.x);
    out[(size_t)row * CD + tid * 2 + 1] = __float2bfloat16((v.y - mu) * rs * gg.y + bv.y);
}

// ---------------- masked softmax over W, in place (bf16), 16B/lane ----------------
__global__ __launch_bounds__(256) void softmax_kernel(__hip_bfloat16* __restrict__ sc)
{
    const int row = blockIdx.x;
    const int t = row % CL;
    const int limit = (t < CK) ? CW : (t - (CK - 1));
    __hip_bfloat16* pr = sc + (size_t)row * CW;
    const int tid = threadIdx.x, wv = tid >> 6, lane = tid & 63;
    const int base = tid * 8;
    const bf16x8 xv = *(const bf16x8*)(pr + base);
    float v[8];
    float mx = -1e30f;
#pragma unroll
    for (int k = 0; k < 8; k++) {
        const float x = (base + k < limit) ? bf2f((unsigned short)xv[k]) : -1e30f;
        v[k] = x; mx = fmaxf(mx, x);
    }
    __shared__ float red[8];
#pragma unroll
    for (int off = 32; off; off >>= 1) mx = fmaxf(mx, __shfl_down(mx, off));
    if (lane == 0) red[wv] = mx;
    __syncthreads();
    mx = fmaxf(fmaxf(red[0], red[1]), fmaxf(red[2], red[3]));
    float s = 0.f;
#pragma unroll
    for (int k = 0; k < 8; k++) {
        const float e = (base + k < limit) ? __expf(v[k] - mx) : 0.f;
        v[k] = e; s += e;
    }
#pragma unroll
    for (int off = 32; off; off >>= 1) s += __shfl_down(s, off);
    if (lane == 0) red[4 + wv] = s;
    __syncthreads();
    s = red[4] + red[5] + red[6] + red[7];
    const float rinv = 1.f / s;
    bf16x8 ov;
#pragma unroll
    for (int k = 0; k < 8; k++) {
        const __hip_bfloat16 b = __float2bfloat16(v[k] * rinv);
        ov[k] = *(const short*)&b;
    }
    *(bf16x8*)(pr + base) = ov;
}

// ---------------- softmax over 64 (branch B), wave per row ----------------
__global__ __launch_bounds__(256) void softmax_b_kernel(__hip_bfloat16* __restrict__ sb)
{
    const int row = blockIdx.x * 4 + (threadIdx.x >> 6);
    const int lane = threadIdx.x & 63;
    __hip_bfloat16* pr = sb + (size_t)row * 64;
    float x = __bfloat162float(pr[lane]);
    float m = x;
#pragma unroll
    for (int off = 32; off; off >>= 1) m = fmaxf(m, __shfl_xor(m, off));
    const float e = __expf(x - m);
    float s = e;
#pragma unroll
    for (int off = 32; off; off >>= 1) s += __shfl_xor(s, off);
    pr[lane] = __float2bfloat16(e / s);
}

// ---------------- final LN + logits ----------------
__global__ __launch_bounds__(256) void final_kernel(const float* __restrict__ h, const float* __restrict__ g,
                                                    const float* __restrict__ bb, const float* __restrict__ wev,
                                                    const float* __restrict__ bev, float* __restrict__ out)
{
    const int idx = blockIdx.x;
    const int b = idx >> 6, t = idx & 63;
    const float* x = h + ((size_t)b * CL + t) * CD;
    const int tid = threadIdx.x, wv = tid >> 6, lane = tid & 63;
    const float2 v = *(const float2*)(x + tid * 2);
    float s = v.x + v.y, s2 = v.x * v.x + v.y * v.y;
    __shared__ float red[8];
#pragma unroll
    for (int off = 32; off; off >>= 1) { s += __shfl_down(s, off); s2 += __shfl_down(s2, off); }
    if (lane == 0) { red[wv] = s; red[4 + wv] = s2; }
    __syncthreads();
    s = red[0] + red[1] + red[2] + red[3];
    s2 = red[4] + red[5] + red[6] + red[7];
    const float mu = s * (1.f / CD);
    const float var = s2 * (1.f / CD) - mu * mu;
    const float rs = rsqrtf(var + 1e-5f);
    const float2 gg = *(const float2*)(g + tid * 2);
    const float2 bv = *(const float2*)(bb + tid * 2);
    const float2 wv2 = *(const float2*)(wev + tid * 2);
    float val = ((v.x - mu) * rs * gg.x + bv.x) * wv2.x + ((v.y - mu) * rs * gg.y + bv.y) * wv2.y;
#pragma unroll
    for (int off = 32; off; off >>= 1) val += __shfl_down(val, off);
    __syncthreads();
    if (lane == 0) red[wv] = val;
    __syncthreads();
    if (tid == 0) out[idx] = red[0] + red[1] + red[2] + red[3] + bev[0];
}

// ---------------- transpose-convert: fp32 [z][R][C] -> bf16 [z][C][R] (separate z strides) ----------------
__global__ void transpose_f32(const float* __restrict__ in, __hip_bfloat16* __restrict__ out,
                              int R, int Cc, long inzs, long outzs)
{
    __shared__ float tile[32][33];
    const size_t zi = (size_t)blockIdx.z * inzs;
    const size_t zo = (size_t)blockIdx.z * outzs;
    const int c0 = blockIdx.x * 32, r0 = blockIdx.y * 32;
    const int tx = threadIdx.x, ty = threadIdx.y;
#pragma unroll
    for (int i = ty; i < 32; i += 8)
        tile[i][tx] = in[zi + (size_t)(r0 + i) * Cc + c0 + tx];
    __syncthreads();
#pragma unroll
    for (int i = ty; i < 32; i += 8)
        out[zo + (size_t)(c0 + i) * R + r0 + tx] = __float2bfloat16(tile[tx][i]);
}

extern "C" void kernel_launch(void* const* d_in, const int* in_sizes, int n_in,
                              void* d_out, int out_size, void* d_ws, size_t ws_size,
                              hipStream_t stream)
{
    const int*   cache = (const int*)d_in[0];
    const int*   seq   = (const int*)d_in[1];
    const float* item  = (const float*)d_in[2];
    const float* cpos  = (const float*)d_in[3];
    const float* spos  = (const float*)d_in[4];
    const float* seg   = (const float*)d_in[5];
    const float* wq_s  = (const float*)d_in[6];
    const float* wk_s  = (const float*)d_in[7];
    const float* wv_s  = (const float*)d_in[8];
    const float* wq_c  = (const float*)d_in[9];
    const float* wk_c  = (const float*)d_in[10];
    const float* wv_c  = (const float*)d_in[11];
    const float* w_out = (const float*)d_in[12];
    const float* b_out = (const float*)d_in[13];
    const float* ln1_g = (const float*)d_in[14];
    const float* ln1_b = (const float*)d_in[15];
    const float* ln2_g = (const float*)d_in[16];
    const float* ln2_b = (const float*)d_in[17];
    const float* w_ff1 = (const float*)d_in[18];
    const float* b_ff1 = (const float*)d_in[19];
    const float* w_ff2 = (const float*)d_in[20];
    const float* b_ff2 = (const float*)d_in[21];
    const float* fin_g = (const float*)d_in[22];
    const float* fin_b = (const float*)d_in[23];
    const float* w_ev  = (const float*)d_in[24];
    const float* b_ev  = (const float*)d_in[25];

    // ---- workspace layout (~237 MiB) ----
    char* p = (char*)d_ws;
    auto alloc = [&](size_t bytes) { char* r = p; p += (bytes + 255) & ~(size_t)255; return (void*)r; };
    float* h    = (float*)alloc((size_t)CROWS * CD * 4);           // 69.2 MB
    short* hnat = (short*)alloc((size_t)CROWS * CD * 2);           // 34.6 MB  (hn, later attn)
    short* q    = (short*)alloc((size_t)CROWS * 512 * 2);          // 34.6 MB  (q_a | q_b)
    short* ka   = (short*)alloc((size_t)CB * CW * CDH * 2);        // 16.8 MB
    short* vt   = (short*)alloc((size_t)CB * CDH * CW * 2);        // 16.8 MB
    short* kb   = (short*)alloc((size_t)CB * 64 * CDH * 2);        // 0.5 MB
    short* vbT  = (short*)alloc((size_t)CB * CDH * 64 * 2);        // 0.5 MB
    short* sb   = (short*)alloc((size_t)CB * CL * 64 * 2);         // 4.3 MB
    short* big  = (short*)alloc((size_t)GB * CL * CW * 2);         // 34.6 MB
    short* wqT  = (short*)alloc((size_t)CNL * 512 * CD * 2);       // 2.1 MB
    short* wksT = (short*)alloc((size_t)CNL * CDH * CD * 2);
    short* wvsT = (short*)alloc((size_t)CNL * CDH * CD * 2);
    short* wkcT = (short*)alloc((size_t)CNL * CDH * CD * 2);
    short* wvcT = (short*)alloc((size_t)CNL * CDH * CD * 2);
    short* woT  = (short*)alloc((size_t)CNL * CD * CD * 2);
    short* wf1T = (short*)alloc((size_t)CNL * CDFF * CD * 2);
    short* wf2T = (short*)alloc((size_t)CNL * CD * CDFF * 2);

    const dim3 tb(32, 8);
    const long zqk = (long)CD * CDH;      // 131072
    const long zqT = (long)512 * CD;      // 262144
    transpose_f32<<<dim3(CDH/32, CD/32, CNL), tb, 0, stream>>>(wq_s, (__hip_bfloat16*)wqT, CD, CDH, zqk, zqT);
    transpose_f32<<<dim3(CDH/32, CD/32, CNL), tb, 0, stream>>>(wq_c, (__hip_bfloat16*)(wqT + (size_t)CDH * CD), CD, CDH, zqk, zqT);
    transpose_f32<<<dim3(CDH/32, CD/32, CNL), tb, 0, stream>>>(wk_s, (__hip_bfloat16*)wksT, CD, CDH, zqk, zqk);
    transpose_f32<<<dim3(CDH/32, CD/32, CNL), tb, 0, stream>>>(wv_s, (__hip_bfloat16*)wvsT, CD, CDH, zqk, zqk);
    transpose_f32<<<dim3(CDH/32, CD/32, CNL), tb, 0, stream>>>(wk_c, (__hip_bfloat16*)wkcT, CD, CDH, zqk, zqk);
    transpose_f32<<<dim3(CDH/32, CD/32, CNL), tb, 0, stream>>>(wv_c, (__hip_bfloat16*)wvcT, CD, CDH, zqk, zqk);
    transpose_f32<<<dim3(CD/32, CD/32, CNL), tb, 0, stream>>>(w_out, (__hip_bfloat16*)woT, CD, CD, (long)CD*CD, (long)CD*CD);
    transpose_f32<<<dim3(CDFF/32, CD/32, CNL), tb, 0, stream>>>(w_ff1, (__hip_bfloat16*)wf1T, CD, CDFF, (long)CD*CDFF, (long)CD*CDFF);
    transpose_f32<<<dim3(CD/32, CDFF/32, CNL), tb, 0, stream>>>(w_ff2, (__hip_bfloat16*)wf2T, CDFF, CD, (long)CD*CDFF, (long)CD*CDFF);

    embed_kernel<<<CROWS, 128, 0, stream>>>(cache, seq, item, cpos, spos, seg, h);

    const int mtilesR = CROWS / 128;          // 264
    const int mtilesL = (CL + 127) / 128;     // 17

    for (int l = 0; l < CNL; ++l) {
        const short* wqTl  = wqT  + (size_t)l * 512 * CD;
        const short* wksTl = wksT + (size_t)l * CDH * CD;
        const short* wvsTl = wvsT + (size_t)l * CDH * CD;
        const short* wkcTl = wkcT + (size_t)l * CDH * CD;
        const short* wvcTl = wvcT + (size_t)l * CDH * CD;
        const short* woTl  = woT  + (size_t)l * CD * CD;
        const short* wf1Tl = wf1T + (size_t)l * CDFF * CD;
        const short* wf2Tl = wf2T + (size_t)l * CD * CDFF;

        ln_kernel<<<CROWS, 256, 0, stream>>>(h, ln1_g + l * CD, ln1_b + l * CD, (__hip_bfloat16*)hnat);

        // q = hn @ [wq_s | wq_c]   (CROWS x 512)
        gemm_bt<<<dim3(512/128, mtilesR, 1), 256, 0, stream>>>(hnat, wqTl, q, nullptr,
            CROWS, 512, CD, CD, CD, 512, 0, 0, 0, 1.f, 0);
        // k_a from hn_seq (batched over 16)
        gemm_bt<<<dim3(CDH/128, CW/128, CB), 256, 0, stream>>>(hnat + (size_t)CK * CD, wksTl, ka, nullptr,
            CW, CDH, CD, CD, CD, CDH, (long)CL * CD, 0, (long)CW * CDH, 1.f, 0);
        // k_b  (M=64, N=256)
        gemm_bt<<<dim3(CDH/128, 1, CB), 256, 0, stream>>>(hnat, wkcTl, kb, nullptr,
            64, CDH, CD, CD, CD, CDH, (long)CL * CD, 0, (long)64 * CDH, 1.f, 0);
        // vbT[d][key] = v_b^T  (M=256, N=64)
        gemm_bt<<<dim3(1, CDH/128, CB), 256, 0, stream>>>(wvcTl, hnat, vbT, nullptr,
            CDH, 64, CD, CD, CD, 64, 0, (long)CL * CD, (long)CDH * 64, 1.f, 0);
        // vt[d][w] = v_a^T  (M=256, N=2048)
        gemm_bt<<<dim3(CW/128, CDH/128, CB), 256, 0, stream>>>(wvsTl, hnat + (size_t)CK * CD, vt, nullptr,
            CDH, CW, CD, CD, CD, CW, 0, (long)CL * CD, (long)CDH * CW, 1.f, 0);

        // ---- branch B: scores_b = (q_b @ k_b^T)*scale -> softmax64 -> @ v_b ----
        gemm_bt<<<dim3(1, mtilesL, CB), 256, 0, stream>>>(q + CDH, kb, sb, nullptr,
            CL, 64, CDH, 512, CDH, 64, (long)CL * 512, (long)64 * CDH, (long)CL * 64, 0.0625f, 2);
        softmax_b_kernel<<<(CB * CL) / 4, 256, 0, stream>>>((__hip_bfloat16*)sb);
        gemm_bt<<<dim3(CDH/128, mtilesL, CB), 256, 0, stream>>>(sb, vbT, hnat + CDH, nullptr,
            CL, CDH, 64, 64, 64, CD, (long)CL * 64, (long)CDH * 64, (long)CL * CD, 1.f, 0);

        // ---- branch A in groups of GB batches -> hnat cols [0,256) ----
        for (int g = 0; g < CB / GB; ++g) {
            const short* qag = q  + (size_t)g * GB * CL * 512;
            const short* kag = ka + (size_t)g * GB * CW * CDH;
            const short* vtg = vt + (size_t)g * GB * CDH * CW;
            short* attg = hnat + (size_t)g * GB * CL * CD;
            gemm_bt<<<dim3(CW/128, mtilesL, GB), 256, 0, stream>>>(qag, kag, big, nullptr,
                CL, CW, CDH, 512, CDH, CW, (long)CL * 512, (long)CW * CDH, (long)CL * CW, 0.0625f, 2);
            softmax_kernel<<<GB * CL, 256, 0, stream>>>((__hip_bfloat16*)big);
            gemm_bt<<<dim3(CDH/128, mtilesL, GB), 256, 0, stream>>>(big, vtg, attg, nullptr,
                CL, CDH, CW, CW, CW, CD, (long)CL * CW, (long)CDH * CW, (long)CL * CD, 1.f, 0);
        }

        // h += attn @ w_out + b_out
        gemm_bt<<<dim3(CD/128, mtilesR, 1), 256, 0, stream>>>(hnat, woTl, h, b_out + l * CD,
            CROWS, CD, CD, CD, CD, CD, 0, 0, 0, 1.f, 3);

        ln_kernel<<<CROWS, 256, 0, stream>>>(h, ln2_g + l * CD, ln2_b + l * CD, (__hip_bfloat16*)hnat);

        // FFN in 4 row chunks sharing `big`
        for (int c = 0; c < 4; ++c) {
            const size_t r0 = (size_t)c * RCH;
            gemm_bt<<<dim3(CDFF/128, RCH/128, 1), 256, 0, stream>>>(hnat + r0 * CD, wf1Tl, big, b_ff1 + l * CDFF,
                RCH, CDFF, CD, CD, CD, CDFF, 0, 0, 0, 1.f, 1);
            gemm_bt<<<dim3(CD/128, RCH/128, 1), 256, 0, stream>>>(big, wf2Tl, h + r0 * CD, b_ff2 + l * CD,
                RCH, CD, CDFF, CDFF, CDFF, CD, 0, 0, 0, 1.f, 3);
        }
    }

    final_kernel<<<CB * CK, 256, 0, stream>>>(h, fin_g, fin_b, w_ev, b_ev, (float*)d_out);
}

// Round 4
// 4695.116 us; speedup vs baseline: 1.2294x; 1.1093x over previous
//
#include <hip/hip_runtime.h>
#include <hip/hip_bf16.h>
#include <cstdint>

#define CB 16
#define CK 64
#define CW 2048
#define CL 2112
#define CD 512
#define CDH 256
#define CDFF 2048
#define CNL 4
#define CROWS (CB*CL)
#define GB 4                 // batches per attention group
#define RCH (CROWS/4)        // FFN row chunk (8448 = 66*128)

typedef __attribute__((ext_vector_type(8))) short bf16x8;
typedef __attribute__((ext_vector_type(4))) float f32x4;

__device__ __forceinline__ float bf2f(unsigned short u) {
    union { unsigned int i; float f; } x; x.i = ((unsigned int)u) << 16; return x.f;
}

__device__ __forceinline__ void load_lds16(const void* g, void* l) {
    __builtin_amdgcn_global_load_lds(
        (const __attribute__((address_space(1))) void*)g,
        (__attribute__((address_space(3))) void*)l, 16, 0, 0);
}

// ---------------- GEMM: C[MxN] = A[MxK] @ Bt[NxK]^T, bf16 in, fp32 acc ----------------
// epi 0: C bf16 = acc
// epi 1: C bf16 = relu(acc + bias[col])
// epi 2: C bf16 = acc * scale
// epi 3: C fp32 += acc + bias[col]     (in-place residual)
// epi 4: C fp32 atomicAdd (split-K over blockIdx.z; bias added by slice z==0)
// LDS tiles are XOR-swizzled: 16B chunk c of row r lives at physical chunk c^(r&7)
// -> ds_read_b128 lanes spread over all 32 banks (2 lanes/bank = free).
#define BM 128
#define BN 128
#define BKG 64

__global__ __launch_bounds__(256) void gemm_bt(
    const short* __restrict__ A, const short* __restrict__ Bt, void* __restrict__ C,
    const float* __restrict__ bias, int M, int N, int Kd,
    int lda, int ldb, int ldc, long sA, long sB, long sC, float scale, int epi,
    int ksplit)
{
    __shared__ short lA[BM * BKG];
    __shared__ short lB[BN * BKG];
    const int tid = threadIdx.x;
    const int wave = tid >> 6, lane = tid & 63;
    const int wy = wave >> 1, wx = wave & 1;
    const int lr = lane & 15, quad = lane >> 4;
    const int m0 = blockIdx.y * BM, n0 = blockIdx.x * BN;
    const int z = blockIdx.z;
    const short* Ab = A + (size_t)z * sA;
    const short* Bb = Bt + (size_t)z * sB;

    f32x4 acc[4][4];
#pragma unroll
    for (int i = 0; i < 4; i++)
#pragma unroll
        for (int j = 0; j < 4; j++) acc[i][j] = (f32x4){0.f, 0.f, 0.f, 0.f};

    // staging: lane -> (row sRow, swizzled source chunk) so that LDS slot lane*16B
    // holds chunk (lane&7)^(sRow) of row sRow  (sRow = lane>>3 in the 8-row segment)
    const int sRow = lane >> 3;                       // 0..7
    const int sCol = (((lane & 7) ^ sRow) << 3);      // swizzled chunk * 8 shorts

    int kbeg = 0, kend = Kd;
    if (ksplit > 1) { const int kc = Kd / ksplit; kbeg = z * kc; kend = kbeg + kc; }

    for (int k0 = kbeg; k0 < kend; k0 += BKG) {
        __syncthreads();
#pragma unroll
        for (int n = 0; n < 4; ++n) {
            const int c = wave * 4 + n;
            int ar = m0 + c * 8 + sRow; if (ar > M - 1) ar = M - 1;
            load_lds16(Ab + (size_t)ar * lda + k0 + sCol, lA + c * 512);
            int br = n0 + c * 8 + sRow; if (br > N - 1) br = N - 1;
            load_lds16(Bb + (size_t)br * ldb + k0 + sCol, lB + c * 512);
        }
        __syncthreads();
#pragma unroll
        for (int kk = 0; kk < BKG; kk += 32) {
            const int k4 = kk >> 3;                   // 0 or 4
            bf16x8 av[4], bv[4];
#pragma unroll
            for (int i = 0; i < 4; i++) {
                const int ri = wy * 64 + i * 16 + lr;
                av[i] = *(const bf16x8*)&lA[ri * BKG + ((((k4 + quad) ^ (ri & 7)) << 3))];
            }
#pragma unroll
            for (int j = 0; j < 4; j++) {
                const int rj = wx * 64 + j * 16 + lr;
                bv[j] = *(const bf16x8*)&lB[rj * BKG + ((((k4 + quad) ^ (rj & 7)) << 3))];
            }
#pragma unroll
            for (int i = 0; i < 4; i++)
#pragma unroll
                for (int j = 0; j < 4; j++)
                    acc[i][j] = __builtin_amdgcn_mfma_f32_16x16x32_bf16(av[i], bv[j], acc[i][j], 0, 0, 0);
        }
    }

    const int colBase = n0 + wx * 64 + lr;
    if (epi == 3) {
        float* Cp = (float*)C + (size_t)z * sC;
#pragma unroll
        for (int i = 0; i < 4; i++) {
            const int row0 = m0 + wy * 64 + i * 16 + quad * 4;
#pragma unroll
            for (int j = 0; j < 4; j++) {
                const int col = colBase + j * 16;
                if (col >= N) continue;
                const float bv_ = bias ? bias[col] : 0.f;
#pragma unroll
                for (int r = 0; r < 4; r++) {
                    const int row = row0 + r;
                    if (row < M) Cp[(size_t)row * ldc + col] += acc[i][j][r] + bv_;
                }
            }
        }
    } else if (epi == 4) {
        float* Cp = (float*)C;
#pragma unroll
        for (int i = 0; i < 4; i++) {
            const int row0 = m0 + wy * 64 + i * 16 + quad * 4;
#pragma unroll
            for (int j = 0; j < 4; j++) {
                const int col = colBase + j * 16;
                if (col >= N) continue;
                const float bv_ = (bias && z == 0) ? bias[col] : 0.f;
#pragma unroll
                for (int r = 0; r < 4; r++) {
                    const int row = row0 + r;
                    if (row < M) atomicAdd(&Cp[(size_t)row * ldc + col], acc[i][j][r] + bv_);
                }
            }
        }
    } else {
        __hip_bfloat16* Cp = (__hip_bfloat16*)C + (size_t)z * sC;
#pragma unroll
        for (int i = 0; i < 4; i++) {
            const int row0 = m0 + wy * 64 + i * 16 + quad * 4;
#pragma unroll
            for (int j = 0; j < 4; j++) {
                const int col = colBase + j * 16;
                if (col >= N) continue;
                const float bv_ = (epi == 1) ? bias[col] : 0.f;
#pragma unroll
                for (int r = 0; r < 4; r++) {
                    const int row = row0 + r;
                    if (row < M) {
                        float v = acc[i][j][r];
                        if (epi == 1) { v += bv_; v = v > 0.f ? v : 0.f; }
                        else if (epi == 2) v *= scale;
                        Cp[(size_t)row * ldc + col] = __float2bfloat16(v);
                    }
                }
            }
        }
    }
}

// ---------------- embedding ----------------
__global__ void embed_kernel(const int* __restrict__ cache, const int* __restrict__ seq,
                             const float* __restrict__ item, const float* __restrict__ cpos,
                             const float* __restrict__ spos, const float* __restrict__ seg,
                             float* __restrict__ h)
{
    const int row = blockIdx.x;
    const int b = row / CL, t = row - b * CL;
    const int d = threadIdx.x * 4;
    int id; const float* pos; const float* sg;
    if (t < CK) { id = cache[b * CK + t]; pos = cpos + (size_t)t * CD; sg = seg; }
    else { const int tt = t - CK; id = seq[b * CW + tt]; pos = spos + (size_t)tt * CD; sg = seg + CD; }
    const float4 ev = *(const float4*)(item + (size_t)id * CD + d);
    const float4 pv = *(const float4*)(pos + d);
    const float4 sv = *(const float4*)(sg + d);
    float4 r; r.x = ev.x + pv.x + sv.x; r.y = ev.y + pv.y + sv.y;
    r.z = ev.z + pv.z + sv.z; r.w = ev.w + pv.w + sv.w;
    *(float4*)(h + (size_t)row * CD + d) = r;
}

// ---------------- layernorm -> bf16 ----------------
__global__ __launch_bounds__(256) void ln_kernel(const float* __restrict__ h, const float* __restrict__ g,
                                                 const float* __restrict__ bb, __hip_bfloat16* __restrict__ out)
{
    const int row = blockIdx.x;
    const float* x = h + (size_t)row * CD;
    const int tid = threadIdx.x, wv = tid >> 6, lane = tid & 63;
    const float2 v = *(const float2*)(x + tid * 2);
    float s = v.x + v.y, s2 = v.x * v.x + v.y * v.y;
    __shared__ float red[8];
#pragma unroll
    for (int off = 32; off; off >>= 1) { s += __shfl_down(s, off); s2 += __shfl_down(s2, off); }
    if (lane == 0) { red[wv] = s; red[4 + wv] = s2; }
    __syncthreads();
    s = red[0] + red[1] + red[2] + red[3];
    s2 = red[4] + red[5] + red[6] + red[7];
    const float mu = s * (1.f / CD);
    const float var = s2 * (1.f / CD) - mu * mu;
    const float rs = rsqrtf(var + 1e-5f);
    const float2 gg = *(const float2*)(g + tid * 2);
    const float2 bv = *(const float2*)(bb + tid * 2);
    out[(size_t)row * CD + tid * 2 + 0] = __float2bfloat16((v.x - mu) * rs * gg.x + bv.x);
    out[(size_t)row * CD + tid * 2 + 1] = __float2bfloat16((v.y - mu) * rs * gg.y + bv.y);
}

// ---------------- masked softmax over W, in place (bf16), 16B/lane ----------------
__global__ __launch_bounds__(256) void softmax_kernel(__hip_bfloat16* __restrict__ sc)
{
    const int row = blockIdx.x;
    const int t = row % CL;
    const int limit = (t < CK) ? CW : (t - (CK - 1));
    __hip_bfloat16* pr = sc + (size_t)row * CW;
    const int tid = threadIdx.x, wv = tid >> 6, lane = tid & 63;
    const int base = tid * 8;
    const bf16x8 xv = *(const bf16x8*)(pr + base);
    float v[8];
    float mx = -1e30f;
#pragma unroll
    for (int k = 0; k < 8; k++) {
        const float x = (base + k < limit) ? bf2f((unsigned short)xv[k]) : -1e30f;
        v[k] = x; mx = fmaxf(mx, x);
    }
    __shared__ float red[8];
#pragma unroll
    for (int off = 32; off; off >>= 1) mx = fmaxf(mx, __shfl_down(mx, off));
    if (lane == 0) red[wv] = mx;
    __syncthreads();
    mx = fmaxf(fmaxf(red[0], red[1]), fmaxf(red[2], red[3]));
    float s = 0.f;
#pragma unroll
    for (int k = 0; k < 8; k++) {
        const float e = (base + k < limit) ? __expf(v[k] - mx) : 0.f;
        v[k] = e; s += e;
    }
#pragma unroll
    for (int off = 32; off; off >>= 1) s += __shfl_down(s, off);
    if (lane == 0) red[4 + wv] = s;
    __syncthreads();
    s = red[4] + red[5] + red[6] + red[7];
    const float rinv = 1.f / s;
    bf16x8 ov;
#pragma unroll
    for (int k = 0; k < 8; k++) {
        const __hip_bfloat16 b = __float2bfloat16(v[k] * rinv);
        ov[k] = *(const short*)&b;
    }
    *(bf16x8*)(pr + base) = ov;
}

// ---------------- softmax over 64 (branch B), wave per row ----------------
__global__ __launch_bounds__(256) void softmax_b_kernel(__hip_bfloat16* __restrict__ sb)
{
    const int row = blockIdx.x * 4 + (threadIdx.x >> 6);
    const int lane = threadIdx.x & 63;
    __hip_bfloat16* pr = sb + (size_t)row * 64;
    float x = __bfloat162float(pr[lane]);
    float m = x;
#pragma unroll
    for (int off = 32; off; off >>= 1) m = fmaxf(m, __shfl_xor(m, off));
    const float e = __expf(x - m);
    float s = e;
#pragma unroll
    for (int off = 32; off; off >>= 1) s += __shfl_xor(s, off);
    pr[lane] = __float2bfloat16(e / s);
}

// ---------------- final LN + logits ----------------
__global__ __launch_bounds__(256) void final_kernel(const float* __restrict__ h, const float* __restrict__ g,
                                                    const float* __restrict__ bb, const float* __restrict__ wev,
                                                    const float* __restrict__ bev, float* __restrict__ out)
{
    const int idx = blockIdx.x;
    const int b = idx >> 6, t = idx & 63;
    const float* x = h + ((size_t)b * CL + t) * CD;
    const int tid = threadIdx.x, wv = tid >> 6, lane = tid & 63;
    const float2 v = *(const float2*)(x + tid * 2);
    float s = v.x + v.y, s2 = v.x * v.x + v.y * v.y;
    __shared__ float red[8];
#pragma unroll
    for (int off = 32; off; off >>= 1) { s += __shfl_down(s, off); s2 += __shfl_down(s2, off); }
    if (lane == 0) { red[wv] = s; red[4 + wv] = s2; }
    __syncthreads();
    s = red[0] + red[1] + red[2] + red[3];
    s2 = red[4] + red[5] + red[6] + red[7];
    const float mu = s * (1.f / CD);
    const float var = s2 * (1.f / CD) - mu * mu;
    const float rs = rsqrtf(var + 1e-5f);
    const float2 gg = *(const float2*)(g + tid * 2);
    const float2 bv = *(const float2*)(bb + tid * 2);
    const float2 wv2 = *(const float2*)(wev + tid * 2);
    float val = ((v.x - mu) * rs * gg.x + bv.x) * wv2.x + ((v.y - mu) * rs * gg.y + bv.y) * wv2.y;
#pragma unroll
    for (int off = 32; off; off >>= 1) val += __shfl_down(val, off);
    __syncthreads();
    if (lane == 0) red[wv] = val;
    __syncthreads();
    if (tid == 0) out[idx] = red[0] + red[1] + red[2] + red[3] + bev[0];
}

// ---------------- transpose-convert: fp32 [z][R][C] -> bf16 [z][C][R] (separate z strides) ----------------
__global__ void transpose_f32(const float* __restrict__ in, __hip_bfloat16* __restrict__ out,
                              int R, int Cc, long inzs, long outzs)
{
    __shared__ float tile[32][33];
    const size_t zi = (size_t)blockIdx.z * inzs;
    const size_t zo = (size_t)blockIdx.z * outzs;
    const int c0 = blockIdx.x * 32, r0 = blockIdx.y * 32;
    const int tx = threadIdx.x, ty = threadIdx.y;
#pragma unroll
    for (int i = ty; i < 32; i += 8)
        tile[i][tx] = in[zi + (size_t)(r0 + i) * Cc + c0 + tx];
    __syncthreads();
#pragma unroll
    for (int i = ty; i < 32; i += 8)
        out[zo + (size_t)(c0 + i) * R + r0 + tx] = __float2bfloat16(tile[tx][i]);
}

extern "C" void kernel_launch(void* const* d_in, const int* in_sizes, int n_in,
                              void* d_out, int out_size, void* d_ws, size_t ws_size,
                              hipStream_t stream)
{
    const int*   cache = (const int*)d_in[0];
    const int*   seq   = (const int*)d_in[1];
    const float* item  = (const float*)d_in[2];
    const float* cpos  = (const float*)d_in[3];
    const float* spos  = (const float*)d_in[4];
    const float* seg   = (const float*)d_in[5];
    const float* wq_s  = (const float*)d_in[6];
    const float* wk_s  = (const float*)d_in[7];
    const float* wv_s  = (const float*)d_in[8];
    const float* wq_c  = (const float*)d_in[9];
    const float* wk_c  = (const float*)d_in[10];
    const float* wv_c  = (const float*)d_in[11];
    const float* w_out = (const float*)d_in[12];
    const float* b_out = (const float*)d_in[13];
    const float* ln1_g = (const float*)d_in[14];
    const float* ln1_b = (const float*)d_in[15];
    const float* ln2_g = (const float*)d_in[16];
    const float* ln2_b = (const float*)d_in[17];
    const float* w_ff1 = (const float*)d_in[18];
    const float* b_ff1 = (const float*)d_in[19];
    const float* w_ff2 = (const float*)d_in[20];
    const float* b_ff2 = (const float*)d_in[21];
    const float* fin_g = (const float*)d_in[22];
    const float* fin_b = (const float*)d_in[23];
    const float* w_ev  = (const float*)d_in[24];
    const float* b_ev  = (const float*)d_in[25];

    // ---- workspace layout (~237 MiB) ----
    char* p = (char*)d_ws;
    auto alloc = [&](size_t bytes) { char* r = p; p += (bytes + 255) & ~(size_t)255; return (void*)r; };
    float* h    = (float*)alloc((size_t)CROWS * CD * 4);           // 69.2 MB
    short* hnat = (short*)alloc((size_t)CROWS * CD * 2);           // 34.6 MB  (hn, later attn)
    short* q    = (short*)alloc((size_t)CROWS * 512 * 2);          // 34.6 MB  (q_a | q_b)
    short* ka   = (short*)alloc((size_t)CB * CW * CDH * 2);        // 16.8 MB
    short* vt   = (short*)alloc((size_t)CB * CDH * CW * 2);        // 16.8 MB
    short* kb   = (short*)alloc((size_t)CB * 64 * CDH * 2);        // 0.5 MB
    short* vbT  = (short*)alloc((size_t)CB * CDH * 64 * 2);        // 0.5 MB
    short* sb   = (short*)alloc((size_t)CB * CL * 64 * 2);         // 4.3 MB
    short* big  = (short*)alloc((size_t)GB * CL * CW * 2);         // 34.6 MB
    short* wqT  = (short*)alloc((size_t)CNL * 512 * CD * 2);       // 2.1 MB
    short* wksT = (short*)alloc((size_t)CNL * CDH * CD * 2);
    short* wvsT = (short*)alloc((size_t)CNL * CDH * CD * 2);
    short* wkcT = (short*)alloc((size_t)CNL * CDH * CD * 2);
    short* wvcT = (short*)alloc((size_t)CNL * CDH * CD * 2);
    short* woT  = (short*)alloc((size_t)CNL * CD * CD * 2);
    short* wf1T = (short*)alloc((size_t)CNL * CDFF * CD * 2);
    short* wf2T = (short*)alloc((size_t)CNL * CD * CDFF * 2);

    const dim3 tb(32, 8);
    const long zqk = (long)CD * CDH;      // 131072
    const long zqT = (long)512 * CD;      // 262144
    transpose_f32<<<dim3(CDH/32, CD/32, CNL), tb, 0, stream>>>(wq_s, (__hip_bfloat16*)wqT, CD, CDH, zqk, zqT);
    transpose_f32<<<dim3(CDH/32, CD/32, CNL), tb, 0, stream>>>(wq_c, (__hip_bfloat16*)(wqT + (size_t)CDH * CD), CD, CDH, zqk, zqT);
    transpose_f32<<<dim3(CDH/32, CD/32, CNL), tb, 0, stream>>>(wk_s, (__hip_bfloat16*)wksT, CD, CDH, zqk, zqk);
    transpose_f32<<<dim3(CDH/32, CD/32, CNL), tb, 0, stream>>>(wv_s, (__hip_bfloat16*)wvsT, CD, CDH, zqk, zqk);
    transpose_f32<<<dim3(CDH/32, CD/32, CNL), tb, 0, stream>>>(wk_c, (__hip_bfloat16*)wkcT, CD, CDH, zqk, zqk);
    transpose_f32<<<dim3(CDH/32, CD/32, CNL), tb, 0, stream>>>(wv_c, (__hip_bfloat16*)wvcT, CD, CDH, zqk, zqk);
    transpose_f32<<<dim3(CD/32, CD/32, CNL), tb, 0, stream>>>(w_out, (__hip_bfloat16*)woT, CD, CD, (long)CD*CD, (long)CD*CD);
    transpose_f32<<<dim3(CDFF/32, CD/32, CNL), tb, 0, stream>>>(w_ff1, (__hip_bfloat16*)wf1T, CD, CDFF, (long)CD*CDFF, (long)CD*CDFF);
    transpose_f32<<<dim3(CD/32, CDFF/32, CNL), tb, 0, stream>>>(w_ff2, (__hip_bfloat16*)wf2T, CDFF, CD, (long)CD*CDFF, (long)CD*CDFF);

    embed_kernel<<<CROWS, 128, 0, stream>>>(cache, seq, item, cpos, spos, seg, h);

    const int mtilesR = CROWS / 128;          // 264
    const int mtilesL = (CL + 127) / 128;     // 17

    for (int l = 0; l < CNL; ++l) {
        const short* wqTl  = wqT  + (size_t)l * 512 * CD;
        const short* wksTl = wksT + (size_t)l * CDH * CD;
        const short* wvsTl = wvsT + (size_t)l * CDH * CD;
        const short* wkcTl = wkcT + (size_t)l * CDH * CD;
        const short* wvcTl = wvcT + (size_t)l * CDH * CD;
        const short* woTl  = woT  + (size_t)l * CD * CD;
        const short* wf1Tl = wf1T + (size_t)l * CDFF * CD;
        const short* wf2Tl = wf2T + (size_t)l * CD * CDFF;

        ln_kernel<<<CROWS, 256, 0, stream>>>(h, ln1_g + l * CD, ln1_b + l * CD, (__hip_bfloat16*)hnat);

        // q = hn @ [wq_s | wq_c]   (CROWS x 512)
        gemm_bt<<<dim3(512/128, mtilesR, 1), 256, 0, stream>>>(hnat, wqTl, q, nullptr,
            CROWS, 512, CD, CD, CD, 512, 0, 0, 0, 1.f, 0, 1);
        // k_a from hn_seq (batched over 16)
        gemm_bt<<<dim3(CDH/128, CW/128, CB), 256, 0, stream>>>(hnat + (size_t)CK * CD, wksTl, ka, nullptr,
            CW, CDH, CD, CD, CD, CDH, (long)CL * CD, 0, (long)CW * CDH, 1.f, 0, 1);
        // k_b  (M=64, N=256)
        gemm_bt<<<dim3(CDH/128, 1, CB), 256, 0, stream>>>(hnat, wkcTl, kb, nullptr,
            64, CDH, CD, CD, CD, CDH, (long)CL * CD, 0, (long)64 * CDH, 1.f, 0, 1);
        // vbT[d][key] = v_b^T  (M=256, N=64)
        gemm_bt<<<dim3(1, CDH/128, CB), 256, 0, stream>>>(wvcTl, hnat, vbT, nullptr,
            CDH, 64, CD, CD, CD, 64, 0, (long)CL * CD, (long)CDH * 64, 1.f, 0, 1);
        // vt[d][w] = v_a^T  (M=256, N=2048)
        gemm_bt<<<dim3(CW/128, CDH/128, CB), 256, 0, stream>>>(wvsTl, hnat + (size_t)CK * CD, vt, nullptr,
            CDH, CW, CD, CD, CD, CW, 0, (long)CL * CD, (long)CDH * CW, 1.f, 0, 1);

        // ---- branch B: scores_b = (q_b @ k_b^T)*scale -> softmax64 -> @ v_b ----
        gemm_bt<<<dim3(1, mtilesL, CB), 256, 0, stream>>>(q + CDH, kb, sb, nullptr,
            CL, 64, CDH, 512, CDH, 64, (long)CL * 512, (long)64 * CDH, (long)CL * 64, 0.0625f, 2, 1);
        softmax_b_kernel<<<(CB * CL) / 4, 256, 0, stream>>>((__hip_bfloat16*)sb);
        gemm_bt<<<dim3(CDH/128, mtilesL, CB), 256, 0, stream>>>(sb, vbT, hnat + CDH, nullptr,
            CL, CDH, 64, 64, 64, CD, (long)CL * 64, (long)CDH * 64, (long)CL * CD, 1.f, 0, 1);

        // ---- branch A in groups of GB batches -> hnat cols [0,256) ----
        for (int g = 0; g < CB / GB; ++g) {
            const short* qag = q  + (size_t)g * GB * CL * 512;
            const short* kag = ka + (size_t)g * GB * CW * CDH;
            const short* vtg = vt + (size_t)g * GB * CDH * CW;
            short* attg = hnat + (size_t)g * GB * CL * CD;
            gemm_bt<<<dim3(CW/128, mtilesL, GB), 256, 0, stream>>>(qag, kag, big, nullptr,
                CL, CW, CDH, 512, CDH, CW, (long)CL * 512, (long)CW * CDH, (long)CL * CW, 0.0625f, 2, 1);
            softmax_kernel<<<GB * CL, 256, 0, stream>>>((__hip_bfloat16*)big);
            gemm_bt<<<dim3(CDH/128, mtilesL, GB), 256, 0, stream>>>(big, vtg, attg, nullptr,
                CL, CDH, CW, CW, CW, CD, (long)CL * CW, (long)CDH * CW, (long)CL * CD, 1.f, 0, 1);
        }

        // h += attn @ w_out + b_out
        gemm_bt<<<dim3(CD/128, mtilesR, 1), 256, 0, stream>>>(hnat, woTl, h, b_out + l * CD,
            CROWS, CD, CD, CD, CD, CD, 0, 0, 0, 1.f, 3, 1);

        ln_kernel<<<CROWS, 256, 0, stream>>>(h, ln2_g + l * CD, ln2_b + l * CD, (__hip_bfloat16*)hnat);

        // FFN in 4 row chunks sharing `big`; FF2 is split-K(4) via atomicAdd
        for (int c = 0; c < 4; ++c) {
            const size_t r0 = (size_t)c * RCH;
            gemm_bt<<<dim3(CDFF/128, RCH/128, 1), 256, 0, stream>>>(hnat + r0 * CD, wf1Tl, big, b_ff1 + l * CDFF,
                RCH, CDFF, CD, CD, CD, CDFF, 0, 0, 0, 1.f, 1, 1);
            gemm_bt<<<dim3(CD/128, RCH/128, 4), 256, 0, stream>>>(big, wf2Tl, h + r0 * CD, b_ff2 + l * CD,
                RCH, CD, CDFF, CDFF, CDFF, CD, 0, 0, 0, 1.f, 4, 4);
        }
    }

    final_kernel<<<CB * CK, 256, 0, stream>>>(h, fin_g, fin_b, w_ev, b_ev, (float*)d_out);
}